// Round 8
// baseline (1250.500 us; speedup 1.0000x reference)
//
#include <hip/hip_runtime.h>
#include <stdint.h>

#define N_ROWS 100000
#define D_IN 512
#define H_DIM 2048
#define HEADS 4
#define NSEG 10000

typedef unsigned short u16;
typedef uint32_t u32;
typedef __attribute__((ext_vector_type(4))) float f32x4;
typedef __attribute__((ext_vector_type(8))) __bf16 bf16x8;
typedef __attribute__((ext_vector_type(8))) u16 u16x8;
typedef __attribute__((ext_vector_type(2))) u32 u32x2;
typedef __attribute__((ext_vector_type(4))) u32 u32x4;

__device__ __forceinline__ u16 f2bf(float f) {
  union { float f; uint32_t u; } v; v.f = f;
  uint32_t r = (v.u + 0x7FFF + ((v.u >> 16) & 1)) >> 16;
  return (u16)r;
}
__device__ __forceinline__ float bf2f(u16 u) {
  union { uint32_t u; float f; } v; v.u = ((uint32_t)u) << 16;
  return v.f;
}

// ---------------- init: bias1 = b1 + alpha*W1[512,:], zero segmax/segsum ---
__global__ void init_misc(const float* __restrict__ W1, const float* __restrict__ b1,
                          const float* __restrict__ alpha, float* __restrict__ bias1,
                          float* __restrict__ segmax, float* __restrict__ segsum) {
  int i = blockIdx.x * 256 + threadIdx.x;
  if (i < NSEG * HEADS) { segmax[i] = 0.f; segsum[i] = 0.f; }
  if (i < H_DIM) bias1[i] = b1[i] + alpha[0] * W1[(size_t)D_IN * H_DIM + i];
}

// ---------------- transpose + cast: in[R][C] fp32 -> out[C][R] bf16 --------
__global__ __launch_bounds__(256) void transpose_cast(const float* __restrict__ in,
                                                      u16* __restrict__ outT,
                                                      int R, int Cc) {
  __shared__ float t[32][33];
  const int c0 = blockIdx.x * 32, r0 = blockIdx.y * 32;
  const int tx = threadIdx.x, ty = threadIdx.y;  // 32 x 8
#pragma unroll
  for (int i = 0; i < 4; ++i)
    t[ty + 8 * i][tx] = in[(size_t)(r0 + ty + 8 * i) * Cc + c0 + tx];
  __syncthreads();
#pragma unroll
  for (int i = 0; i < 4; ++i) {
    int oc = ty + 8 * i;
    outT[(size_t)(c0 + oc) * R + r0 + tx] = f2bf(t[tx][oc]);
  }
}

// ============================================================================
// Fused MLP, one block per 128-row panel of x:
//   h2[128][512] = relu( relu(x[128][512]·W1t^T + bias1) · W2t^T + b2 )
// 8 waves (512 thr). LDS: x-panel [128][512]bf16 (128KB, XOR-swizzled) +
// h1c chunk [128][64]bf16 (16KB, XOR-swizzled) = 144 KB.
// Weights are L2-resident (2 MB each); fed as PER-LANE dwordx4 register
// fragments (no LDS staging, no vmcnt drains at barriers — loads pipeline
// freely across the lgkmcnt-only barriers).
// Per chunk c (64 h-cols):
//  GEMM1 (swapped): mfma(W1frag, xfrag) -> acc1: lane&15 = x-row,
//    (lane>>4)*4+r = h-col -> 4 CONSECUTIVE h-cols per lane -> bias+relu+
//    pack -> ds_write_b64 into h1c (row-major, k-contiguous). Wave role:
//    hg=w&3 (16 h-cols), xg=w>>2 (64 x-rows); W1 redundancy 2x.
//  barrier (lgkmcnt only).
//  GEMM2: mfma(h1cfrag, W2frag) -> acc2[8][4] (128 VGPR, persistent, K-acc
//    over all 32 chunks). Wave role: og=w (64 out-cols), redundancy 1x.
//  barrier (WAR for next chunk's h1c writes).
// Epilogue: bias2+relu -> h2 bf16.
// ============================================================================
__global__ __launch_bounds__(512, 2) void fused_mlp(
    const float* __restrict__ x, const u16* __restrict__ W1t,
    const u16* __restrict__ W2t, const float* __restrict__ bias1,
    const float* __restrict__ b2, u16* __restrict__ h2) {
  __shared__ __align__(16) char smem[147456];
  char* xs = smem;            // [128][1024 B]
  char* h1s = smem + 131072;  // [128][128 B]
  const int tid = threadIdx.x;
  const int w = tid >> 6, l = tid & 63, lr = l & 15, g = l >> 4;
  const int hg = w & 3, xg = w >> 2;  // GEMM1 roles
  const int og = w;                   // GEMM2 out-col group
  const int rowBase = blockIdx.x * 128;

  // ---- prologue: stage x fp32 -> bf16 LDS, swizzled ----
#pragma unroll
  for (int i = 0; i < 16; ++i) {
    int e = i * 4096 + tid * 8;  // flat elem in [0, 65536)
    int row = e >> 9, col = e & 511;
    int gr = rowBase + row; if (gr >= N_ROWS) gr = N_ROWS - 1;
    const float* src = x + (size_t)gr * 512 + col;
    f32x4 a = *(const f32x4*)src;
    f32x4 b = *(const f32x4*)(src + 4);
    u32x4 pk;
    pk[0] = (u32)f2bf(a[0]) | ((u32)f2bf(a[1]) << 16);
    pk[1] = (u32)f2bf(a[2]) | ((u32)f2bf(a[3]) << 16);
    pk[2] = (u32)f2bf(b[0]) | ((u32)f2bf(b[1]) << 16);
    pk[3] = (u32)f2bf(b[2]) | ((u32)f2bf(b[3]) << 16);
    int byte = row * 1024 + col * 2;
    byte ^= (row & 7) << 4;
    *(u32x4*)(xs + byte) = pk;
  }
  __syncthreads();

  f32x4 acc2[8][4] = {};

  for (int c = 0; c < 32; ++c) {
    const int cb = c * 64;

    // ---- GEMM1 chunk (swapped operands) ----
    f32x4 acc1[4] = {};
#pragma unroll
    for (int kk = 0; kk < 16; ++kk) {
      bf16x8 w1f = *(const bf16x8*)(W1t + (size_t)(cb + hg * 16 + lr) * 512 + kk * 32 + g * 8);
      bf16x8 xf0, xf1, xf2, xf3;
      {
        int r0 = xg * 64 + 0 * 16 + lr, b0 = (r0 * 1024 + kk * 64 + g * 16) ^ ((r0 & 7) << 4);
        int r1 = xg * 64 + 1 * 16 + lr, b1_ = (r1 * 1024 + kk * 64 + g * 16) ^ ((r1 & 7) << 4);
        int r2 = xg * 64 + 2 * 16 + lr, b2_ = (r2 * 1024 + kk * 64 + g * 16) ^ ((r2 & 7) << 4);
        int r3 = xg * 64 + 3 * 16 + lr, b3_ = (r3 * 1024 + kk * 64 + g * 16) ^ ((r3 & 7) << 4);
        xf0 = *(const bf16x8*)(xs + b0);
        xf1 = *(const bf16x8*)(xs + b1_);
        xf2 = *(const bf16x8*)(xs + b2_);
        xf3 = *(const bf16x8*)(xs + b3_);
      }
      acc1[0] = __builtin_amdgcn_mfma_f32_16x16x32_bf16(w1f, xf0, acc1[0], 0, 0, 0);
      acc1[1] = __builtin_amdgcn_mfma_f32_16x16x32_bf16(w1f, xf1, acc1[1], 0, 0, 0);
      acc1[2] = __builtin_amdgcn_mfma_f32_16x16x32_bf16(w1f, xf2, acc1[2], 0, 0, 0);
      acc1[3] = __builtin_amdgcn_mfma_f32_16x16x32_bf16(w1f, xf3, acc1[3], 0, 0, 0);
    }
    // bias + relu + pack -> h1c  (lane holds h-cols cb+hg*16+g*4+{0..3} of x-row)
    {
      f32x4 bv = *(const f32x4*)(bias1 + cb + hg * 16 + g * 4);
#pragma unroll
      for (int xi = 0; xi < 4; ++xi) {
        float v0 = fmaxf(acc1[xi][0] + bv[0], 0.f);
        float v1 = fmaxf(acc1[xi][1] + bv[1], 0.f);
        float v2 = fmaxf(acc1[xi][2] + bv[2], 0.f);
        float v3 = fmaxf(acc1[xi][3] + bv[3], 0.f);
        u32x2 p;
        p[0] = (u32)f2bf(v0) | ((u32)f2bf(v1) << 16);
        p[1] = (u32)f2bf(v2) | ((u32)f2bf(v3) << 16);
        int row = xg * 64 + xi * 16 + lr;
        int byte = (row * 128 + hg * 32 + g * 8) ^ ((row & 7) << 4);
        *(u32x2*)(h1s + byte) = p;
      }
    }
    asm volatile("s_waitcnt lgkmcnt(0)" ::: "memory");
    __builtin_amdgcn_sched_barrier(0);
    __builtin_amdgcn_s_barrier();  // h1c RAW

    // ---- GEMM2 accumulate ----
#pragma unroll
    for (int kk2 = 0; kk2 < 2; ++kk2) {
      bf16x8 w2f[4];
#pragma unroll
      for (int ni = 0; ni < 4; ++ni)
        w2f[ni] = *(const bf16x8*)(W2t + (size_t)(og * 64 + ni * 16 + lr) * 2048 + cb + kk2 * 32 + g * 8);
      bf16x8 h1f[8];
#pragma unroll
      for (int mi = 0; mi < 8; ++mi) {
        int row = mi * 16 + lr;
        int byte = (row * 128 + kk2 * 64 + g * 16) ^ ((row & 7) << 4);
        h1f[mi] = *(const bf16x8*)(h1s + byte);
      }
#pragma unroll
      for (int mi = 0; mi < 8; ++mi)
#pragma unroll
        for (int ni = 0; ni < 4; ++ni)
          acc2[mi][ni] = __builtin_amdgcn_mfma_f32_16x16x32_bf16(h1f[mi], w2f[ni], acc2[mi][ni], 0, 0, 0);
    }
    asm volatile("s_waitcnt lgkmcnt(0)" ::: "memory");
    __builtin_amdgcn_sched_barrier(0);
    __builtin_amdgcn_s_barrier();  // h1c WAR
  }

  // ---- epilogue: bias2 + relu -> h2 ----
  float bb[4];
#pragma unroll
  for (int ni = 0; ni < 4; ++ni) bb[ni] = b2[og * 64 + ni * 16 + lr];
#pragma unroll
  for (int mi = 0; mi < 8; ++mi) {
#pragma unroll
    for (int r = 0; r < 4; ++r) {
      int row = rowBase + mi * 16 + g * 4 + r;
      if (row < N_ROWS) {
#pragma unroll
        for (int ni = 0; ni < 4; ++ni) {
          float v = fmaxf(acc2[mi][ni][r] + bb[ni], 0.f);
          h2[(size_t)row * 512 + og * 64 + ni * 16 + lr] = f2bf(v);
        }
      }
    }
  }
}

// ---------------- LayerNorm + 4-head projection + sigmoid + seg-max --------
__global__ __launch_bounds__(256) void ln_att_kernel(
    const u16* __restrict__ h2, const float* __restrict__ gam,
    const float* __restrict__ bet, const float* __restrict__ Wa,
    const float* __restrict__ ba, const int* __restrict__ row,
    float* __restrict__ att, float* __restrict__ segmax, int rows) {
  const int w = threadIdx.x >> 6, l = threadIdx.x & 63;
  const int n = blockIdx.x * 4 + w;
  if (n >= rows) return;
  const u16* hp = h2 + (size_t)n * D_IN + l * 8;
  u16x8 hraw = *(const u16x8*)hp;
  float hv[8];
  float s = 0.f, sq = 0.f;
#pragma unroll
  for (int j = 0; j < 8; ++j) {
    hv[j] = bf2f(hraw[j]);
    s += hv[j];
    sq += hv[j] * hv[j];
  }
#pragma unroll
  for (int off = 32; off >= 1; off >>= 1) {
    s += __shfl_xor(s, off);
    sq += __shfl_xor(sq, off);
  }
  const float mean = s * (1.f / 512.f);
  const float var = sq * (1.f / 512.f) - mean * mean;
  const float rstd = rsqrtf(var + 1e-5f);
  float a0 = 0, a1 = 0, a2 = 0, a3 = 0;
#pragma unroll
  for (int j = 0; j < 8; ++j) {
    int d = l * 8 + j;
    float hn = (hv[j] - mean) * rstd * gam[d] + bet[d];
    f32x4 wv = *(const f32x4*)(Wa + (size_t)d * 4);
    a0 += hn * wv[0]; a1 += hn * wv[1]; a2 += hn * wv[2]; a3 += hn * wv[3];
  }
#pragma unroll
  for (int off = 32; off >= 1; off >>= 1) {
    a0 += __shfl_xor(a0, off); a1 += __shfl_xor(a1, off);
    a2 += __shfl_xor(a2, off); a3 += __shfl_xor(a3, off);
  }
  if (l == 0) {
    int rid = row[n];
    float av[4] = {a0, a1, a2, a3};
#pragma unroll
    for (int h = 0; h < 4; ++h) {
      float z = av[h] + ba[h];
      float sg = 1.f / (1.f + expf(-z));
      att[(size_t)n * 4 + h] = sg;
      atomicMax((int*)&segmax[(size_t)rid * 4 + h], __float_as_int(sg));  // sg > 0 always
    }
  }
}

// ---------------- segment sum of exp ---------------------------------------
__global__ void seg_exp_sum(const float* __restrict__ att, const int* __restrict__ row,
                            const float* __restrict__ segmax, float* __restrict__ segsum) {
  int i = blockIdx.x * 256 + threadIdx.x;
  if (i >= N_ROWS * HEADS) return;
  int n = i >> 2, h = i & 3;
  int rid = row[n];
  float ev = expf(att[i] - segmax[(size_t)rid * 4 + h]);
  atomicAdd(&segsum[(size_t)rid * 4 + h], ev);
}

// ---------------- normalize + head-mean ------------------------------------
__global__ void seg_norm(const float* __restrict__ att, const int* __restrict__ row,
                         const float* __restrict__ segmax, const float* __restrict__ segsum,
                         float* __restrict__ out) {
  int n = blockIdx.x * 256 + threadIdx.x;
  if (n >= N_ROWS) return;
  int rid = row[n];
  float s = 0.f;
#pragma unroll
  for (int h = 0; h < 4; ++h) {
    float ev = expf(att[(size_t)n * 4 + h] - segmax[(size_t)rid * 4 + h]);
    s += ev / segsum[(size_t)rid * 4 + h];
  }
  out[n] = 0.25f * s;
}

extern "C" void kernel_launch(void* const* d_in, const int* in_sizes, int n_in,
                              void* d_out, int out_size, void* d_ws, size_t ws_size,
                              hipStream_t stream) {
  const float* x = (const float*)d_in[0];
  const int* row = (const int*)d_in[1];
  const float* alpha = (const float*)d_in[2];
  const float* W1 = (const float*)d_in[3];
  const float* b1 = (const float*)d_in[4];
  const float* W2 = (const float*)d_in[5];
  const float* b2 = (const float*)d_in[6];
  const float* ln_g = (const float*)d_in[7];
  const float* ln_b = (const float*)d_in[8];
  const float* Wa = (const float*)d_in[9];
  const float* ba = (const float*)d_in[10];
  float* out = (float*)d_out;

  char* ws = (char*)d_ws;
  size_t off = 0;
  auto alloc = [&](size_t bytes) {
    void* p = ws + off;
    off += (bytes + 255) & ~(size_t)255;
    return p;
  };
  u16* W1t = (u16*)alloc((size_t)H_DIM * D_IN * 2);
  u16* W2t = (u16*)alloc((size_t)D_IN * H_DIM * 2);
  float* bias1 = (float*)alloc(H_DIM * 4);
  float* att = (float*)alloc((size_t)N_ROWS * HEADS * 4);
  float* segmax = (float*)alloc(NSEG * HEADS * 4);
  float* segsum = (float*)alloc(NSEG * HEADS * 4);
  u16* h2 = (u16*)alloc((size_t)((N_ROWS + 127) & ~127) * D_IN * 2);

  init_misc<<<(NSEG * HEADS + 255) / 256, 256, 0, stream>>>(W1, b1, alpha, bias1, segmax, segsum);
  transpose_cast<<<dim3(H_DIM / 32, D_IN / 32), dim3(32, 8), 0, stream>>>(W1, W1t, D_IN, H_DIM);
  transpose_cast<<<dim3(D_IN / 32, H_DIM / 32), dim3(32, 8), 0, stream>>>(W2, W2t, H_DIM, D_IN);

  const int nblk = (N_ROWS + 127) / 128;  // 782
  fused_mlp<<<nblk, 512, 0, stream>>>(x, W1t, W2t, bias1, b2, h2);

  ln_att_kernel<<<(N_ROWS + 3) / 4, 256, 0, stream>>>(
      h2, ln_g, ln_b, Wa, ba, row, att, segmax, N_ROWS);
  seg_exp_sum<<<(N_ROWS * HEADS + 255) / 256, 256, 0, stream>>>(att, row, segmax, segsum);
  seg_norm<<<(N_ROWS + 255) / 256, 256, 0, stream>>>(att, row, segmax, segsum, out);
}

// Round 10
// 742.496 us; speedup vs baseline: 1.6842x; 1.6842x over previous
//
#include <hip/hip_runtime.h>
#include <stdint.h>

#define N_ROWS 100000
#define D_IN 512
#define H_DIM 2048
#define HEADS 4
#define NSEG 10000

typedef unsigned short u16;
typedef __attribute__((ext_vector_type(4))) float f32x4;
typedef __attribute__((ext_vector_type(8))) __bf16 bf16x8;
typedef __attribute__((ext_vector_type(8))) u16 u16x8;
typedef __attribute__((ext_vector_type(4))) u16 u16x4;

__device__ __forceinline__ u16 f2bf(float f) {
  union { float f; uint32_t u; } v; v.f = f;
  uint32_t r = (v.u + 0x7FFF + ((v.u >> 16) & 1)) >> 16;
  return (u16)r;
}
__device__ __forceinline__ float bf2f(u16 u) {
  union { uint32_t u; float f; } v; v.u = ((uint32_t)u) << 16;
  return v.f;
}

// ---------------- init: bias1 = b1 + alpha*W1[512,:], zero segmax/segsum ---
__global__ void init_misc(const float* __restrict__ W1, const float* __restrict__ b1,
                          const float* __restrict__ alpha, float* __restrict__ bias1,
                          float* __restrict__ segmax, float* __restrict__ segsum) {
  int i = blockIdx.x * 256 + threadIdx.x;
  if (i < NSEG * HEADS) { segmax[i] = 0.f; segsum[i] = 0.f; }
  if (i < H_DIM) bias1[i] = b1[i] + alpha[0] * W1[(size_t)D_IN * H_DIM + i];
}

// ---------------- cast x (fp32) -> xb (bf16) -------------------------------
__global__ void cast_x_kernel(const float* __restrict__ x, u16* __restrict__ xb, long n4) {
  long i = (long)blockIdx.x * 256 + threadIdx.x;
  if (i >= n4) return;
  f32x4 v = *(const f32x4*)(x + i * 4);
  u16x4 o;
  o[0] = f2bf(v[0]); o[1] = f2bf(v[1]); o[2] = f2bf(v[2]); o[3] = f2bf(v[3]);
  *(u16x4*)(xb + i * 4) = o;
}

// ---------------- transpose + cast: in[R][C] fp32 -> out[C][R] bf16 --------
__global__ __launch_bounds__(256) void transpose_cast(const float* __restrict__ in,
                                                      u16* __restrict__ outT,
                                                      int R, int Cc) {
  __shared__ float t[32][33];
  const int c0 = blockIdx.x * 32, r0 = blockIdx.y * 32;
  const int tx = threadIdx.x, ty = threadIdx.y;  // 32 x 8
#pragma unroll
  for (int i = 0; i < 4; ++i)
    t[ty + 8 * i][tx] = in[(size_t)(r0 + ty + 8 * i) * Cc + c0 + tx];
  __syncthreads();
#pragma unroll
  for (int i = 0; i < 4; ++i) {
    int oc = ty + 8 * i;
    outT[(size_t)(c0 + oc) * R + r0 + tx] = f2bf(t[tx][oc]);
  }
}

// ============================================================================
// NT GEMM round-10: r7 structure + ALL tile-(t+1) stages issued at tile-t TOP,
// single end-of-tile vmcnt(0)+barrier gate.
//
// r9 RACE (fixed here): r9 kept B-half1(t) in flight across GATE2(t-1) and
// published it mid-tile at GATE1. But B-half1 = PHYSICAL rows 128-255 of the
// B tile, i.e. the full 64-col strips of waves wn=2,3 — those waves read
// half1 in their bq0 at tile TOP, before GATE1 => read un-landed DMA data.
// Quadrant split (cols 0-31 / 32-63 within each wave strip) does NOT align
// with the half0/half1 staging units. Lesson: gate-late only works if the
// late unit is read late by EVERY wave.
//
// Now: all 4 units of tile t+1 (8 loads/thread) issued at tile-t top; the
// end-of-tile vmcnt(0) waits on loads aged 4 MFMA clusters + 24 ds_reads
// (~1300-1800 cyc > ~900 cyc HBM latency) => near-zero drain stall.
// 256x256 tile, BK=64, 8 waves (2Mx4N), 2 dbuf slots (128 KiB), XOR swizzle
// byte^=((row&7)<<4) (0 bank conflicts, verified r4-r7).
// Slot safety: stages at t top target slot (t+1)&1, whose tile-(t-1) readers
// all retired before the end-of-(t-1) barrier (reads consumed by MFMAs
// pre-barrier). Reads in tile t touch only slot t&1, fully published at the
// end-of-(t-1) gate.
// ============================================================================
#define BARX asm volatile("s_barrier" ::: "memory")

template <int RELU>
__global__ __launch_bounds__(512, 2) void gemm256s(const u16* __restrict__ A,
                                                   const u16* __restrict__ Bt,
                                                   const float* __restrict__ bias,
                                                   u16* __restrict__ C,
                                                   int M, int Nc, int K, int NTN) {
  __shared__ __align__(16) char smem[131072];
  const int tid = threadIdx.x;
  const int w = tid >> 6, l = tid & 63;
  const int wm = w >> 2, wn = w & 3;  // 2 x 4 waves
  const int lr = l & 15, g = l >> 4;

  // T1: bijective XCD swizzle (m204)
  const int nwg = gridDim.x;
  const int orig = blockIdx.x;
  const int qq = nwg >> 3, rr = nwg & 7, xcd = orig & 7, idx = orig >> 3;
  const int wgid = (xcd < rr ? xcd * (qq + 1) : rr * (qq + 1) + (xcd - rr) * qq) + idx;
  const int rowBase = (wgid / NTN) * 256;
  const int colBase = (wgid % NTN) * 256;

  const int NT = K >> 6;  // BK = 64

  // staging source pre-swizzle: LDS byte q within a 16 KiB unit receives
  // global element at o = q ^ ((q>>7 & 7)<<4)  (row = o>>7, kel = (o&127)>>1)
  int s_row[2], s_kel[2];
#pragma unroll
  for (int p = 0; p < 2; ++p) {
    int q = (w * 2 + p) * 1024 + l * 16;
    int o = q ^ (((q >> 7) & 7) << 4);
    s_row[p] = o >> 7;
    s_kel[p] = (o & 127) >> 1;
  }

  auto stageA = [&](int kt, int half) {
    if (kt >= NT) return;
    char* base = smem + (kt & 1) * 65536 + half * 16384;
#pragma unroll
    for (int p = 0; p < 2; ++p) {
      int r = rowBase + half * 128 + s_row[p];
      if (r >= M) r = M - 1;
      const u16* src = A + (size_t)r * K + kt * 64 + s_kel[p];
      __builtin_amdgcn_global_load_lds(
          (const __attribute__((address_space(1))) void*)src,
          (__attribute__((address_space(3))) void*)(base + (w * 2 + p) * 1024), 16, 0, 0);
    }
  };
  auto stageB = [&](int kt, int half) {
    if (kt >= NT) return;
    char* base = smem + (kt & 1) * 65536 + 32768 + half * 16384;
#pragma unroll
    for (int p = 0; p < 2; ++p) {
      int rc = colBase + half * 128 + s_row[p];
      const u16* src = Bt + (size_t)rc * K + kt * 64 + s_kel[p];
      __builtin_amdgcn_global_load_lds(
          (const __attribute__((address_space(1))) void*)src,
          (__attribute__((address_space(3))) void*)(base + (w * 2 + p) * 1024), 16, 0, 0);
    }
  };

  f32x4 acc[8][4] = {};
  bf16x8 af_a[8], af_b[8], bq0[4], bq1[4];

  // prologue: tile0 fully staged + published
  stageA(0, 0); stageA(0, 1); stageB(0, 0); stageB(0, 1);
  asm volatile("s_waitcnt vmcnt(0)" ::: "memory");
  BARX;

  const int aRow = (wm * 128 + lr) * 128;  // byte offset of lane's A row
  const int bRow = (wn * 64 + lr) * 128;
  int ck[2];
  ck[0] = (g ^ (lr & 7)) << 4;        // kk=0 swizzled chunk
  ck[1] = ((4 + g) ^ (lr & 7)) << 4;  // kk=1 swizzled chunk

  for (int t = 0; t < NT; ++t) {
    const char* sa = smem + (t & 1) * 65536;
    const char* sb = sa + 32768;

    // issue ALL of tile t+1's staging now (max age before the tile-end gate)
    stageA(t + 1, 0); stageA(t + 1, 1); stageB(t + 1, 0); stageB(t + 1, 1);

    // Q0 inputs: A[m0] (8) + B[n0] (4)
#pragma unroll
    for (int kk = 0; kk < 2; ++kk) {
#pragma unroll
      for (int mi = 0; mi < 4; ++mi)
        af_a[kk * 4 + mi] = *(const bf16x8*)(sa + aRow + mi * 2048 + ck[kk]);
#pragma unroll
      for (int j = 0; j < 2; ++j)
        bq0[kk * 2 + j] = *(const bf16x8*)(sb + bRow + j * 2048 + ck[kk]);
    }

    // MFMA Q0 (m0, n0)
    __builtin_amdgcn_s_setprio(1);
#pragma unroll
    for (int kk = 0; kk < 2; ++kk)
#pragma unroll
      for (int mi = 0; mi < 4; ++mi)
#pragma unroll
        for (int j = 0; j < 2; ++j)
          acc[mi][j] = __builtin_amdgcn_mfma_f32_16x16x32_bf16(
              af_a[kk * 4 + mi], bq0[kk * 2 + j], acc[mi][j], 0, 0, 0);
    __builtin_amdgcn_s_setprio(0);

    // B[n1] (4)
#pragma unroll
    for (int kk = 0; kk < 2; ++kk)
#pragma unroll
      for (int j = 0; j < 2; ++j)
        bq1[kk * 2 + j] = *(const bf16x8*)(sb + bRow + 4096 + j * 2048 + ck[kk]);

    // MFMA Q1 (m0, n1)
    __builtin_amdgcn_s_setprio(1);
#pragma unroll
    for (int kk = 0; kk < 2; ++kk)
#pragma unroll
      for (int mi = 0; mi < 4; ++mi)
#pragma unroll
        for (int j = 0; j < 2; ++j)
          acc[mi][2 + j] = __builtin_amdgcn_mfma_f32_16x16x32_bf16(
              af_a[kk * 4 + mi], bq1[kk * 2 + j], acc[mi][2 + j], 0, 0, 0);
    __builtin_amdgcn_s_setprio(0);

    // A[m1] (8)
#pragma unroll
    for (int kk = 0; kk < 2; ++kk)
#pragma unroll
      for (int mi = 0; mi < 4; ++mi)
        af_b[kk * 4 + mi] = *(const bf16x8*)(sa + aRow + 8192 + mi * 2048 + ck[kk]);

    // MFMA Q2 (m1, n1) + Q3 (m1, n0)
    __builtin_amdgcn_s_setprio(1);
#pragma unroll
    for (int kk = 0; kk < 2; ++kk)
#pragma unroll
      for (int mi = 0; mi < 4; ++mi)
#pragma unroll
        for (int j = 0; j < 2; ++j)
          acc[4 + mi][2 + j] = __builtin_amdgcn_mfma_f32_16x16x32_bf16(
              af_b[kk * 4 + mi], bq1[kk * 2 + j], acc[4 + mi][2 + j], 0, 0, 0);
#pragma unroll
    for (int kk = 0; kk < 2; ++kk)
#pragma unroll
      for (int mi = 0; mi < 4; ++mi)
#pragma unroll
        for (int j = 0; j < 2; ++j)
          acc[4 + mi][j] = __builtin_amdgcn_mfma_f32_16x16x32_bf16(
              af_b[kk * 4 + mi], bq0[kk * 2 + j], acc[4 + mi][j], 0, 0, 0);
    __builtin_amdgcn_s_setprio(0);

    // single gate: publish tile t+1 (loads aged a full tile; drain ~free)
    if (t + 1 < NT) {
      asm volatile("s_waitcnt vmcnt(0)" ::: "memory");
      BARX;
    }
  }

  // epilogue: bias + optional relu, bf16 store
  float bv[4];
#pragma unroll
  for (int ni = 0; ni < 4; ++ni) bv[ni] = bias[colBase + wn * 64 + ni * 16 + lr];
#pragma unroll
  for (int mi = 0; mi < 8; ++mi) {
#pragma unroll
    for (int r = 0; r < 4; ++r) {
      int row = rowBase + wm * 128 + mi * 16 + g * 4 + r;
      if (row < M) {
#pragma unroll
        for (int ni = 0; ni < 4; ++ni) {
          float v = acc[mi][ni][r] + bv[ni];
          if (RELU) v = fmaxf(v, 0.f);
          C[(size_t)row * Nc + colBase + wn * 64 + ni * 16 + lr] = f2bf(v);
        }
      }
    }
  }
}

// ---------------- LayerNorm + 4-head projection + sigmoid + seg-max --------
__global__ __launch_bounds__(256) void ln_att_kernel(
    const u16* __restrict__ h2, const float* __restrict__ gam,
    const float* __restrict__ bet, const float* __restrict__ Wa,
    const float* __restrict__ ba, const int* __restrict__ row,
    float* __restrict__ att, float* __restrict__ segmax, int rows) {
  const int w = threadIdx.x >> 6, l = threadIdx.x & 63;
  const int n = blockIdx.x * 4 + w;
  if (n >= rows) return;
  const u16* hp = h2 + (size_t)n * D_IN + l * 8;
  u16x8 hraw = *(const u16x8*)hp;
  float hv[8];
  float s = 0.f, sq = 0.f;
#pragma unroll
  for (int j = 0; j < 8; ++j) {
    hv[j] = bf2f(hraw[j]);
    s += hv[j];
    sq += hv[j] * hv[j];
  }
#pragma unroll
  for (int off = 32; off >= 1; off >>= 1) {
    s += __shfl_xor(s, off);
    sq += __shfl_xor(sq, off);
  }
  const float mean = s * (1.f / 512.f);
  const float var = sq * (1.f / 512.f) - mean * mean;
  const float rstd = rsqrtf(var + 1e-5f);
  float a0 = 0, a1 = 0, a2 = 0, a3 = 0;
#pragma unroll
  for (int j = 0; j < 8; ++j) {
    int d = l * 8 + j;
    float hn = (hv[j] - mean) * rstd * gam[d] + bet[d];
    f32x4 wv = *(const f32x4*)(Wa + (size_t)d * 4);
    a0 += hn * wv[0]; a1 += hn * wv[1]; a2 += hn * wv[2]; a3 += hn * wv[3];
  }
#pragma unroll
  for (int off = 32; off >= 1; off >>= 1) {
    a0 += __shfl_xor(a0, off); a1 += __shfl_xor(a1, off);
    a2 += __shfl_xor(a2, off); a3 += __shfl_xor(a3, off);
  }
  if (l == 0) {
    int rid = row[n];
    float av[4] = {a0, a1, a2, a3};
#pragma unroll
    for (int h = 0; h < 4; ++h) {
      float z = av[h] + ba[h];
      float sg = 1.f / (1.f + expf(-z));
      att[(size_t)n * 4 + h] = sg;
      atomicMax((int*)&segmax[(size_t)rid * 4 + h], __float_as_int(sg));  // sg > 0 always
    }
  }
}

// ---------------- segment sum of exp ---------------------------------------
__global__ void seg_exp_sum(const float* __restrict__ att, const int* __restrict__ row,
                            const float* __restrict__ segmax, float* __restrict__ segsum) {
  int i = blockIdx.x * 256 + threadIdx.x;
  if (i >= N_ROWS * HEADS) return;
  int n = i >> 2, h = i & 3;
  int rid = row[n];
  float ev = expf(att[i] - segmax[(size_t)rid * 4 + h]);
  atomicAdd(&segsum[(size_t)rid * 4 + h], ev);
}

// ---------------- normalize + head-mean ------------------------------------
__global__ void seg_norm(const float* __restrict__ att, const int* __restrict__ row,
                         const float* __restrict__ segmax, const float* __restrict__ segsum,
                         float* __restrict__ out) {
  int n = blockIdx.x * 256 + threadIdx.x;
  if (n >= N_ROWS) return;
  int rid = row[n];
  float s = 0.f;
#pragma unroll
  for (int h = 0; h < 4; ++h) {
    float ev = expf(att[(size_t)n * 4 + h] - segmax[(size_t)rid * 4 + h]);
    s += ev / segsum[(size_t)rid * 4 + h];
  }
  out[n] = 0.25f * s;
}

extern "C" void kernel_launch(void* const* d_in, const int* in_sizes, int n_in,
                              void* d_out, int out_size, void* d_ws, size_t ws_size,
                              hipStream_t stream) {
  const float* x = (const float*)d_in[0];
  const int* row = (const int*)d_in[1];
  const float* alpha = (const float*)d_in[2];
  const float* W1 = (const float*)d_in[3];
  const float* b1 = (const float*)d_in[4];
  const float* W2 = (const float*)d_in[5];
  const float* b2 = (const float*)d_in[6];
  const float* ln_g = (const float*)d_in[7];
  const float* ln_b = (const float*)d_in[8];
  const float* Wa = (const float*)d_in[9];
  const float* ba = (const float*)d_in[10];
  float* out = (float*)d_out;

  char* ws = (char*)d_ws;
  size_t off = 0;
  auto alloc = [&](size_t bytes) {
    void* p = ws + off;
    off += (bytes + 255) & ~(size_t)255;
    return p;
  };
  // fixed buffers (~8 MB)
  u16* W1t = (u16*)alloc((size_t)H_DIM * D_IN * 2);
  u16* W2t = (u16*)alloc((size_t)D_IN * H_DIM * 2);
  float* bias1 = (float*)alloc(H_DIM * 4);
  float* att = (float*)alloc((size_t)N_ROWS * HEADS * 4);
  float* segmax = (float*)alloc(NSEG * HEADS * 4);
  float* segsum = (float*)alloc(NSEG * HEADS * 4);

  // slab sizing from remaining ws: per-row 6144 B (xb 1KB + h1 4KB + h2 1KB)
  const size_t per_row = ((size_t)D_IN + H_DIM + D_IN) * 2;
  const size_t reserve = (size_t)1 << 20;
  size_t usable = (ws_size > off + reserve) ? (ws_size - off - reserve) : 0;
  long slab_l = (long)(usable / per_row);
  const int maxslab = (N_ROWS + 255) & ~255;  // 100096
  int slab;
  if (slab_l >= maxslab) slab = maxslab;
  else slab = (int)(slab_l & ~255L);          // round DOWN so allocs fit
  if (slab < 256) slab = 256;                 // last-resort minimum

  u16* xb = (u16*)alloc((size_t)slab * D_IN * 2);
  u16* h1 = (u16*)alloc((size_t)slab * H_DIM * 2);
  u16* h2 = (u16*)alloc((size_t)slab * D_IN * 2);

  init_misc<<<(NSEG * HEADS + 255) / 256, 256, 0, stream>>>(W1, b1, alpha, bias1, segmax, segsum);
  transpose_cast<<<dim3(H_DIM / 32, D_IN / 32), dim3(32, 8), 0, stream>>>(W1, W1t, D_IN, H_DIM);
  transpose_cast<<<dim3(D_IN / 32, H_DIM / 32), dim3(32, 8), 0, stream>>>(W2, W2t, H_DIM, D_IN);

  for (int s0 = 0; s0 < N_ROWS; s0 += slab) {
    int rows = N_ROWS - s0 < slab ? N_ROWS - s0 : slab;
    int ntm = (rows + 255) / 256;
    long n4 = (long)rows * D_IN / 4;
    cast_x_kernel<<<(int)((n4 + 255) / 256), 256, 0, stream>>>(x + (size_t)s0 * D_IN, xb, n4);
    gemm256s<1><<<ntm * (H_DIM / 256), 512, 0, stream>>>(
        xb, W1t, bias1, h1, rows, H_DIM, D_IN, H_DIM / 256);
    gemm256s<1><<<ntm * (D_IN / 256), 512, 0, stream>>>(
        h1, W2t, b2, h2, rows, D_IN, H_DIM, D_IN / 256);
    ln_att_kernel<<<(rows + 3) / 4, 256, 0, stream>>>(
        h2, ln_g, ln_b, Wa, ba, row + s0, att + (size_t)s0 * HEADS, segmax, rows);
  }

  seg_exp_sum<<<(N_ROWS * HEADS + 255) / 256, 256, 0, stream>>>(att, row, segmax, segsum);
  seg_norm<<<(N_ROWS + 255) / 256, 256, 0, stream>>>(att, row, segmax, segsum, out);
}

// Round 11
// 691.579 us; speedup vs baseline: 1.8082x; 1.0736x over previous
//
#include <hip/hip_runtime.h>
#include <stdint.h>

#define N_ROWS 100000
#define D_IN 512
#define H_DIM 2048
#define HEADS 4
#define NSEG 10000

typedef unsigned short u16;
typedef __attribute__((ext_vector_type(4))) float f32x4;
typedef __attribute__((ext_vector_type(8))) __bf16 bf16x8;
typedef __attribute__((ext_vector_type(8))) u16 u16x8;
typedef __attribute__((ext_vector_type(4))) u16 u16x4;

__device__ __forceinline__ u16 f2bf(float f) {
  union { float f; uint32_t u; } v; v.f = f;
  uint32_t r = (v.u + 0x7FFF + ((v.u >> 16) & 1)) >> 16;
  return (u16)r;
}
__device__ __forceinline__ float bf2f(u16 u) {
  union { uint32_t u; float f; } v; v.u = ((uint32_t)u) << 16;
  return v.f;
}

// ---------------- init: bias1 = b1 + alpha*W1[512,:], zero segmax/segsum ---
__global__ void init_misc(const float* __restrict__ W1, const float* __restrict__ b1,
                          const float* __restrict__ alpha, float* __restrict__ bias1,
                          float* __restrict__ segmax, float* __restrict__ segsum) {
  int i = blockIdx.x * 256 + threadIdx.x;
  if (i < NSEG * HEADS) { segmax[i] = 0.f; segsum[i] = 0.f; }
  if (i < H_DIM) bias1[i] = b1[i] + alpha[0] * W1[(size_t)D_IN * H_DIM + i];
}

// ---------------- cast x (fp32) -> xb (bf16) -------------------------------
__global__ void cast_x_kernel(const float* __restrict__ x, u16* __restrict__ xb, long n4) {
  long i = (long)blockIdx.x * 256 + threadIdx.x;
  if (i >= n4) return;
  f32x4 v = *(const f32x4*)(x + i * 4);
  u16x4 o;
  o[0] = f2bf(v[0]); o[1] = f2bf(v[1]); o[2] = f2bf(v[2]); o[3] = f2bf(v[3]);
  *(u16x4*)(xb + i * 4) = o;
}

// ---------------- transpose + cast: in[R][C] fp32 -> out[C][R] bf16 --------
__global__ __launch_bounds__(256) void transpose_cast(const float* __restrict__ in,
                                                      u16* __restrict__ outT,
                                                      int R, int Cc) {
  __shared__ float t[32][33];
  const int c0 = blockIdx.x * 32, r0 = blockIdx.y * 32;
  const int tx = threadIdx.x, ty = threadIdx.y;  // 32 x 8
#pragma unroll
  for (int i = 0; i < 4; ++i)
    t[ty + 8 * i][tx] = in[(size_t)(r0 + ty + 8 * i) * Cc + c0 + tx];
  __syncthreads();
#pragma unroll
  for (int i = 0; i < 4; ++i) {
    int oc = ty + 8 * i;
    outT[(size_t)(c0 + oc) * R + r0 + tx] = f2bf(t[tx][oc]);
  }
}

// ============================================================================
// NT GEMM round-11: HIGH-OCCUPANCY m97-style 128x128 tile, BK=64, 4 waves
// (256 thr, 2x2), SINGLE-buffer LDS 32 KiB -> target 4 blocks/CU (16 waves).
//
// Rationale: r4-r10 (256^2 tile, 128KB LDS, 1 block/CU = 2 waves/SIMD) pinned
// at MfmaUtil 27-29% across 5 different hand schedules — with 2 waves/SIMD
// all pipe overlap must come from the explicit schedule, and it didn't
// deliver. m97 (912 TF, 128^2, 16KB LDS, ~3-4 blocks/CU) gets overlap FREE
// from cross-block wave interleave (m114): while one block drains its
// barrier/vmcnt, other blocks' waves compute. This kernel = m97 skeleton +
// BK=64 (128-B rows -> r10's XOR swizzle applies verbatim, 0 bank conflicts;
// BK=32's 64-B rows have an UNFIXABLE 8-way read conflict - m98's 1.7e7) +
// simple 2-__syncthreads K-step, compiler-scheduled interior.
// LDS: A[128][64]bf16 at 0 (16 KiB unit), B at +16384. Swizzle (r10-proven):
// LDS byte q receives global elem at o = q ^ (((q>>7)&7)<<4).
// ============================================================================
template <int RELU>
__global__ __launch_bounds__(256, 3) void gemm128h(const u16* __restrict__ A,
                                                   const u16* __restrict__ Bt,
                                                   const float* __restrict__ bias,
                                                   u16* __restrict__ C,
                                                   int M, int Nc, int K, int NTN) {
  __shared__ __align__(16) char smem[32768];
  const int tid = threadIdx.x;
  const int w = tid >> 6, l = tid & 63;
  const int wm = w >> 1, wn = w & 1;  // 2 x 2 waves
  const int lr = l & 15, g = l >> 4;

  // T1: bijective XCD swizzle (m204)
  const int nwg = gridDim.x;
  const int orig = blockIdx.x;
  const int qq = nwg >> 3, rr = nwg & 7, xcd = orig & 7, idx = orig >> 3;
  const int wgid = (xcd < rr ? xcd * (qq + 1) : rr * (qq + 1) + (xcd - rr) * qq) + idx;
  const int rowBase = (wgid / NTN) * 128;
  const int colBase = (wgid % NTN) * 128;

  const int NT = K >> 6;  // BK = 64

  // staging source pre-swizzle: 4 chunks/thread per 16 KiB unit.
  // chunk p: lds offset q = p*4096 + w*1024 + l*16 (wave-uniform base + l*16)
  int s_row[4], s_kel[4];
#pragma unroll
  for (int p = 0; p < 4; ++p) {
    int q = p * 4096 + w * 1024 + l * 16;
    int o = q ^ (((q >> 7) & 7) << 4);
    s_row[p] = o >> 7;        // row in [0,128)
    s_kel[p] = (o & 127) >> 1;  // k elem in [0,64)
  }

  f32x4 acc[4][4] = {};

  const int aRow = (wm * 64 + lr) * 128;  // byte offset of lane's A row base
  const int bRow = (wn * 64 + lr) * 128;
  int ck[2];
  ck[0] = (g ^ (lr & 7)) << 4;        // kk=0 swizzled 16B chunk
  ck[1] = ((4 + g) ^ (lr & 7)) << 4;  // kk=1 swizzled 16B chunk

  for (int t = 0; t < NT; ++t) {
    __syncthreads();  // WAR: all waves done reading previous tile
    // stage tile t: A unit + B unit (4+4 gll instructions per thread)
#pragma unroll
    for (int p = 0; p < 4; ++p) {
      int r = rowBase + s_row[p];
      if (r >= M) r = M - 1;
      const u16* asrc = A + (size_t)r * K + t * 64 + s_kel[p];
      __builtin_amdgcn_global_load_lds(
          (const __attribute__((address_space(1))) void*)asrc,
          (__attribute__((address_space(3))) void*)(smem + p * 4096 + w * 1024), 16, 0, 0);
    }
#pragma unroll
    for (int p = 0; p < 4; ++p) {
      int rc = colBase + s_row[p];
      const u16* bsrc = Bt + (size_t)rc * K + t * 64 + s_kel[p];
      __builtin_amdgcn_global_load_lds(
          (const __attribute__((address_space(1))) void*)bsrc,
          (__attribute__((address_space(3))) void*)(smem + 16384 + p * 4096 + w * 1024), 16, 0, 0);
    }
    __syncthreads();  // publish (compiler inserts vmcnt(0) drain; hidden by
                      // co-resident blocks' compute at 3-4 blocks/CU)

    // compute: per kk, 4 A-frags + 4 B-frags, 16 MFMA
#pragma unroll
    for (int kk = 0; kk < 2; ++kk) {
      bf16x8 af[4], bf[4];
#pragma unroll
      for (int mi = 0; mi < 4; ++mi)
        af[mi] = *(const bf16x8*)(smem + aRow + mi * 2048 + ck[kk]);
#pragma unroll
      for (int ni = 0; ni < 4; ++ni)
        bf[ni] = *(const bf16x8*)(smem + 16384 + bRow + ni * 2048 + ck[kk]);
      __builtin_amdgcn_s_setprio(1);
#pragma unroll
      for (int mi = 0; mi < 4; ++mi)
#pragma unroll
        for (int ni = 0; ni < 4; ++ni)
          acc[mi][ni] = __builtin_amdgcn_mfma_f32_16x16x32_bf16(af[mi], bf[ni], acc[mi][ni], 0, 0, 0);
      __builtin_amdgcn_s_setprio(0);
    }
  }

  // epilogue: bias + optional relu, bf16 store
  float bv[4];
#pragma unroll
  for (int ni = 0; ni < 4; ++ni) bv[ni] = bias[colBase + wn * 64 + ni * 16 + lr];
#pragma unroll
  for (int mi = 0; mi < 4; ++mi) {
#pragma unroll
    for (int r = 0; r < 4; ++r) {
      int row = rowBase + wm * 64 + mi * 16 + g * 4 + r;
      if (row < M) {
#pragma unroll
        for (int ni = 0; ni < 4; ++ni) {
          float v = acc[mi][ni][r] + bv[ni];
          if (RELU) v = fmaxf(v, 0.f);
          C[(size_t)row * Nc + colBase + wn * 64 + ni * 16 + lr] = f2bf(v);
        }
      }
    }
  }
}

// ---------------- LayerNorm + 4-head projection + sigmoid + seg-max --------
__global__ __launch_bounds__(256) void ln_att_kernel(
    const u16* __restrict__ h2, const float* __restrict__ gam,
    const float* __restrict__ bet, const float* __restrict__ Wa,
    const float* __restrict__ ba, const int* __restrict__ row,
    float* __restrict__ att, float* __restrict__ segmax, int rows) {
  const int w = threadIdx.x >> 6, l = threadIdx.x & 63;
  const int n = blockIdx.x * 4 + w;
  if (n >= rows) return;
  const u16* hp = h2 + (size_t)n * D_IN + l * 8;
  u16x8 hraw = *(const u16x8*)hp;
  float hv[8];
  float s = 0.f, sq = 0.f;
#pragma unroll
  for (int j = 0; j < 8; ++j) {
    hv[j] = bf2f(hraw[j]);
    s += hv[j];
    sq += hv[j] * hv[j];
  }
#pragma unroll
  for (int off = 32; off >= 1; off >>= 1) {
    s += __shfl_xor(s, off);
    sq += __shfl_xor(sq, off);
  }
  const float mean = s * (1.f / 512.f);
  const float var = sq * (1.f / 512.f) - mean * mean;
  const float rstd = rsqrtf(var + 1e-5f);
  float a0 = 0, a1 = 0, a2 = 0, a3 = 0;
#pragma unroll
  for (int j = 0; j < 8; ++j) {
    int d = l * 8 + j;
    float hn = (hv[j] - mean) * rstd * gam[d] + bet[d];
    f32x4 wv = *(const f32x4*)(Wa + (size_t)d * 4);
    a0 += hn * wv[0]; a1 += hn * wv[1]; a2 += hn * wv[2]; a3 += hn * wv[3];
  }
#pragma unroll
  for (int off = 32; off >= 1; off >>= 1) {
    a0 += __shfl_xor(a0, off); a1 += __shfl_xor(a1, off);
    a2 += __shfl_xor(a2, off); a3 += __shfl_xor(a3, off);
  }
  if (l == 0) {
    int rid = row[n];
    float av[4] = {a0, a1, a2, a3};
#pragma unroll
    for (int h = 0; h < 4; ++h) {
      float z = av[h] + ba[h];
      float sg = 1.f / (1.f + expf(-z));
      att[(size_t)n * 4 + h] = sg;
      atomicMax((int*)&segmax[(size_t)rid * 4 + h], __float_as_int(sg));  // sg > 0 always
    }
  }
}

// ---------------- segment sum of exp ---------------------------------------
__global__ void seg_exp_sum(const float* __restrict__ att, const int* __restrict__ row,
                            const float* __restrict__ segmax, float* __restrict__ segsum) {
  int i = blockIdx.x * 256 + threadIdx.x;
  if (i >= N_ROWS * HEADS) return;
  int n = i >> 2, h = i & 3;
  int rid = row[n];
  float ev = expf(att[i] - segmax[(size_t)rid * 4 + h]);
  atomicAdd(&segsum[(size_t)rid * 4 + h], ev);
}

// ---------------- normalize + head-mean ------------------------------------
__global__ void seg_norm(const float* __restrict__ att, const int* __restrict__ row,
                         const float* __restrict__ segmax, const float* __restrict__ segsum,
                         float* __restrict__ out) {
  int n = blockIdx.x * 256 + threadIdx.x;
  if (n >= N_ROWS) return;
  int rid = row[n];
  float s = 0.f;
#pragma unroll
  for (int h = 0; h < 4; ++h) {
    float ev = expf(att[(size_t)n * 4 + h] - segmax[(size_t)rid * 4 + h]);
    s += ev / segsum[(size_t)rid * 4 + h];
  }
  out[n] = 0.25f * s;
}

extern "C" void kernel_launch(void* const* d_in, const int* in_sizes, int n_in,
                              void* d_out, int out_size, void* d_ws, size_t ws_size,
                              hipStream_t stream) {
  const float* x = (const float*)d_in[0];
  const int* row = (const int*)d_in[1];
  const float* alpha = (const float*)d_in[2];
  const float* W1 = (const float*)d_in[3];
  const float* b1 = (const float*)d_in[4];
  const float* W2 = (const float*)d_in[5];
  const float* b2 = (const float*)d_in[6];
  const float* ln_g = (const float*)d_in[7];
  const float* ln_b = (const float*)d_in[8];
  const float* Wa = (const float*)d_in[9];
  const float* ba = (const float*)d_in[10];
  float* out = (float*)d_out;

  char* ws = (char*)d_ws;
  size_t off = 0;
  auto alloc = [&](size_t bytes) {
    void* p = ws + off;
    off += (bytes + 255) & ~(size_t)255;
    return p;
  };
  // fixed buffers (~8 MB)
  u16* W1t = (u16*)alloc((size_t)H_DIM * D_IN * 2);
  u16* W2t = (u16*)alloc((size_t)D_IN * H_DIM * 2);
  float* bias1 = (float*)alloc(H_DIM * 4);
  float* att = (float*)alloc((size_t)N_ROWS * HEADS * 4);
  float* segmax = (float*)alloc(NSEG * HEADS * 4);
  float* segsum = (float*)alloc(NSEG * HEADS * 4);

  // slab sizing from remaining ws: per-row 6144 B (xb 1KB + h1 4KB + h2 1KB)
  const size_t per_row = ((size_t)D_IN + H_DIM + D_IN) * 2;
  const size_t reserve = (size_t)1 << 20;
  size_t usable = (ws_size > off + reserve) ? (ws_size - off - reserve) : 0;
  long slab_l = (long)(usable / per_row);
  const int maxslab = (N_ROWS + 127) & ~127;  // 100096
  int slab;
  if (slab_l >= maxslab) slab = maxslab;
  else slab = (int)(slab_l & ~127L);          // round DOWN so allocs fit
  if (slab < 128) slab = 128;                 // last-resort minimum

  u16* xb = (u16*)alloc((size_t)slab * D_IN * 2);
  u16* h1 = (u16*)alloc((size_t)slab * H_DIM * 2);
  u16* h2 = (u16*)alloc((size_t)slab * D_IN * 2);

  init_misc<<<(NSEG * HEADS + 255) / 256, 256, 0, stream>>>(W1, b1, alpha, bias1, segmax, segsum);
  transpose_cast<<<dim3(H_DIM / 32, D_IN / 32), dim3(32, 8), 0, stream>>>(W1, W1t, D_IN, H_DIM);
  transpose_cast<<<dim3(D_IN / 32, H_DIM / 32), dim3(32, 8), 0, stream>>>(W2, W2t, H_DIM, D_IN);

  for (int s0 = 0; s0 < N_ROWS; s0 += slab) {
    int rows = N_ROWS - s0 < slab ? N_ROWS - s0 : slab;
    int ntm = (rows + 127) / 128;
    long n4 = (long)rows * D_IN / 4;
    cast_x_kernel<<<(int)((n4 + 255) / 256), 256, 0, stream>>>(x + (size_t)s0 * D_IN, xb, n4);
    gemm128h<1><<<ntm * (H_DIM / 128), 256, 0, stream>>>(
        xb, W1t, bias1, h1, rows, H_DIM, D_IN, H_DIM / 128);
    gemm128h<1><<<ntm * (D_IN / 128), 256, 0, stream>>>(
        h1, W2t, b2, h2, rows, D_IN, H_DIM, D_IN / 128);
    ln_att_kernel<<<(rows + 3) / 4, 256, 0, stream>>>(
        h2, ln_g, ln_b, Wa, ba, row + s0, att + (size_t)s0 * HEADS, segmax, rows);
  }

  seg_exp_sum<<<(N_ROWS * HEADS + 255) / 256, 256, 0, stream>>>(att, row, segmax, segsum);
  seg_norm<<<(N_ROWS + 255) / 256, 256, 0, stream>>>(att, row, segmax, segsum, out);
}